// Round 1
// baseline (165.770 us; speedup 1.0000x reference)
//
#include <hip/hip_runtime.h>
#include <stdint.h>

#define BATCH 32
#define NH    32
#define KVH   8
#define QPK   4
#define DH    128
#define BS    128
#define NEG   (-1e30f)
#define SCALEF 0.08838834764831845f  // 1/sqrt(128)

#define GAS __attribute__((address_space(1)))
#define LAS __attribute__((address_space(3)))

// Stage one KV block's K (128 tokens x 128 f32 = 64KB) into LDS.
// LDS layout is linear rows of 512B; global source granule is pre-swizzled
// (j ^ (t&7)) so that QK's per-token ds_read_b128 is bank-conflict-free.
__device__ __forceinline__ void stage_k(const float* __restrict__ kc, int pb, int g,
                                        float* buf, int wave, int lane) {
  const float* base = kc + ((size_t)pb * BS) * (KVH * DH) + (size_t)g * DH;
#pragma unroll
  for (int i = 0; i < 16; ++i) {
    const int seg = wave * 16 + i;            // 1KB segment = 2 token rows
    const int t   = 2 * seg + (lane >> 5);    // token row this lane feeds
    const int sg  = (lane & 31) ^ (t & 7);    // swizzled source granule (16B)
    const float* gp = base + (size_t)t * (KVH * DH) + sg * 4;
    __builtin_amdgcn_global_load_lds((const GAS void*)gp,
                                     (LAS void*)(buf + seg * 256), 16, 0, 0);
  }
}

__global__ __launch_bounds__(256, 1)
void pa_alibi_decode(const float* __restrict__ query,
                     const float* __restrict__ key_cache,
                     const float* __restrict__ value_cache,
                     const float* __restrict__ alibi_blocks,
                     const float* __restrict__ alibi_slopes,
                     const int* __restrict__ block_list,
                     const int* __restrict__ block_groups,
                     const int* __restrict__ block_usage,
                     float* __restrict__ out,
                     int U) {
  __shared__ __align__(16) float Kbuf[2][BS * DH];   // 128 KiB double buffer
  __shared__ __align__(16) float q_lds[QPK * DH];    // scaled query, 2 KiB
  __shared__ __align__(16) float p_lds[BS * QPK];    // softmax weights, 2 KiB
  __shared__ float combO[4][QPK][DH];                // per-wave partial O
  __shared__ float combM[4][QPK];
  __shared__ float combS[4][QPK];
  __shared__ int   ulist[512];
  __shared__ int   ucount;

  const int tid  = threadIdx.x;
  const int wave = tid >> 6;
  const int lane = tid & 63;
  const int b    = blockIdx.x >> 3;
  const int g    = blockIdx.x & 7;

  // ---- gather this sequence's entries of block_list (order-preserving) ----
  if (wave == 0) {
    int cnt = 0;
    for (int base = 0; base < U; base += 64) {
      const int u = base + lane;
      const bool match = (u < U) && (block_groups[u] == b);
      const unsigned long long mk = __ballot(match);
      if (match) {
        const int pre = __popcll(mk & ((1ull << lane) - 1ull));
        ulist[cnt + pre] = u;
      }
      cnt += __popcll(mk);
    }
    if (lane == 0) ucount = cnt;
  }

  // ---- scaled query -> LDS (heads g*4..g*4+3 are contiguous) ----
  {
    const float* qsrc = query + ((size_t)b * NH + g * QPK) * DH;
    for (int e = tid; e < QPK * DH; e += 256) q_lds[e] = qsrc[e] * SCALEF;
  }

  float slope[QPK];
#pragma unroll
  for (int qh = 0; qh < QPK; ++qh) slope[qh] = alibi_slopes[g * QPK + qh];

  __syncthreads();

  const int nblk = ucount;

  float m[QPK], s[QPK], O[QPK][4];
#pragma unroll
  for (int qh = 0; qh < QPK; ++qh) {
    m[qh] = NEG; s[qh] = 0.f;
#pragma unroll
    for (int k = 0; k < 4; ++k) O[qh][k] = 0.f;
  }

  int cur = 0;
  if (nblk > 0) stage_k(key_cache, block_list[ulist[0]], g, Kbuf[0], wave, lane);
  __syncthreads();  // drains vmcnt -> chunk 0 staged

  for (int c = 0; c < nblk; ++c) {
    const int u     = ulist[c];
    const int pb    = block_list[u];
    const int usage = block_usage[u];

    // issue next block's K stage BEFORE compute so HBM stays busy under QK
    if (c + 1 < nblk)
      stage_k(key_cache, block_list[ulist[c + 1]], g, Kbuf[cur ^ 1], wave, lane);

    // ---- QK: 2 lanes per token (d halves), 32 tokens per wave ----
    const int tt   = wave * 32 + (lane & 31);
    const int half = lane >> 5;
    const int swz  = tt & 7;
    const float* krow = &Kbuf[cur][tt * DH];
    float acc[QPK] = {0.f, 0.f, 0.f, 0.f};
#pragma unroll
    for (int i = 0; i < 16; ++i) {
      const int j = half * 16 + i;
      const float4 kv = *(const float4*)&krow[(j ^ swz) * 4];
#pragma unroll
      for (int qh = 0; qh < QPK; ++qh) {
        const float4 qv = *(const float4*)&q_lds[qh * DH + j * 4];
        acc[qh] += kv.x * qv.x + kv.y * qv.y + kv.z * qv.z + kv.w * qv.w;
      }
    }

    const float ab    = alibi_blocks[(size_t)u * BS + tt];
    const bool  valid = tt < usage;
    float p[QPK];
#pragma unroll
    for (int qh = 0; qh < QPK; ++qh) {
      float sc = acc[qh] + __shfl_xor(acc[qh], 32);
      sc += ab * slope[qh];
      if (!valid) sc = NEG;
      float cm = sc;
#pragma unroll
      for (int off = 1; off < 64; off <<= 1) cm = fmaxf(cm, __shfl_xor(cm, off));
      const float mnew = fmaxf(m[qh], cm);
      const float r    = __expf(m[qh] - mnew);
      m[qh] = mnew;
      p[qh] = valid ? __expf(sc - mnew) : 0.f;
      s[qh] = s[qh] * r + ((lane < 32) ? p[qh] : 0.f);
#pragma unroll
      for (int k = 0; k < 4; ++k) O[qh][k] *= r;
    }
    if (lane < 32)
      *(float4*)&p_lds[tt * 4] = make_float4(p[0], p[1], p[2], p[3]);

    __syncthreads();  // p visible; next-K stage drained (vmcnt(0) at barrier)

    // ---- AV: stream V from global; lane owns d = 4*(lane&31)+k, token parity by half ----
    {
      const float* vbase = value_cache
          + ((size_t)pb * BS + wave * 32 + half) * (KVH * DH)
          + (size_t)g * DH + (lane & 31) * 4;
#pragma unroll
      for (int tp = 0; tp < 16; ++tp) {
        const int tk = wave * 32 + 2 * tp + half;
        const float4 pv = *(const float4*)&p_lds[tk * 4];
        const float4 vv = *(const float4*)&vbase[(size_t)tp * 2 * (KVH * DH)];
        O[0][0] += pv.x * vv.x; O[0][1] += pv.x * vv.y; O[0][2] += pv.x * vv.z; O[0][3] += pv.x * vv.w;
        O[1][0] += pv.y * vv.x; O[1][1] += pv.y * vv.y; O[1][2] += pv.y * vv.z; O[1][3] += pv.y * vv.w;
        O[2][0] += pv.z * vv.x; O[2][1] += pv.z * vv.y; O[2][2] += pv.z * vv.z; O[2][3] += pv.z * vv.w;
        O[3][0] += pv.w * vv.x; O[3][1] += pv.w * vv.y; O[3][2] += pv.w * vv.z; O[3][3] += pv.w * vv.w;
      }
    }
    __syncthreads();  // protect p_lds before next iteration's writes
    cur ^= 1;
  }

  // ---- per-wave finalize ----
#pragma unroll
  for (int qh = 0; qh < QPK; ++qh) {
    float sv = s[qh];
#pragma unroll
    for (int off = 1; off < 64; off <<= 1) sv += __shfl_xor(sv, off);
#pragma unroll
    for (int k = 0; k < 4; ++k) O[qh][k] += __shfl_xor(O[qh][k], 32);
    if (lane < 32) {
#pragma unroll
      for (int k = 0; k < 4; ++k) combO[wave][qh][(lane & 31) * 4 + k] = O[qh][k];
    }
    if (lane == 0) { combM[wave][qh] = m[qh]; combS[wave][qh] = sv; }
  }
  __syncthreads();

  // ---- cross-wave flash combine + output ----
  for (int e = tid; e < QPK * DH; e += 256) {
    const int qh = e >> 7;
    const int d  = e & 127;
    float M = combM[0][qh];
#pragma unroll
    for (int w = 1; w < 4; ++w) M = fmaxf(M, combM[w][qh]);
    float S = 0.f, Ov = 0.f;
#pragma unroll
    for (int w = 0; w < 4; ++w) {
      const float f = __expf(combM[w][qh] - M);
      S  += f * combS[w][qh];
      Ov += f * combO[w][qh][d];
    }
    out[((size_t)b * NH + g * QPK + qh) * DH + d] = Ov / S;
  }
}

extern "C" void kernel_launch(void* const* d_in, const int* in_sizes, int n_in,
                              void* d_out, int out_size, void* d_ws, size_t ws_size,
                              hipStream_t stream) {
  (void)n_in; (void)out_size; (void)d_ws; (void)ws_size;
  const float* query        = (const float*)d_in[0];
  const float* key_cache    = (const float*)d_in[1];
  const float* value_cache  = (const float*)d_in[2];
  const float* alibi_blocks = (const float*)d_in[3];
  const float* alibi_slopes = (const float*)d_in[4];
  const int*   block_list   = (const int*)d_in[5];
  const int*   block_groups = (const int*)d_in[6];
  const int*   block_usage  = (const int*)d_in[7];
  float*       out          = (float*)d_out;
  const int U = in_sizes[5];

  pa_alibi_decode<<<dim3(BATCH * KVH), dim3(256), 0, stream>>>(
      query, key_cache, value_cache, alibi_blocks, alibi_slopes,
      block_list, block_groups, block_usage, out, U);
}

// Round 2
// 118.377 us; speedup vs baseline: 1.4004x; 1.4004x over previous
//
#include <hip/hip_runtime.h>
#include <stdint.h>

#define BATCH 32
#define NH    32
#define KVH   8
#define QPK   4
#define DH    128
#define BS    128
#define NEG   (-1e30f)
#define SCALEF 0.08838834764831845f  // 1/sqrt(128)
#define MAXU  512

#define GAS __attribute__((address_space(1)))
#define LAS __attribute__((address_space(3)))

// Per-wave independent pipeline: each wave owns tokens [w*32, w*32+32) of every
// KV block of its (seq, kv-head). No barriers in the main loop; the only wait
// is a robust s_waitcnt vmcnt(0) at iteration top (K for the current block was
// staged one full iteration earlier). K is staged into per-wave LDS slices via
// global_load_lds with a full 32-granule XOR swizzle (LDS(t,c) = global(t,c^t))
// so QK's per-token ds_read_b128 is bank-conflict-free. V is loaded to
// registers early (issued before the K-prefetch so V-consume waits are
// vmcnt(16) and never drain the prefetch) and consumed after softmax.
__global__ __launch_bounds__(256, 1)
void pa_alibi_decode(const float* __restrict__ query,
                     const float* __restrict__ key_cache,
                     const float* __restrict__ value_cache,
                     const float* __restrict__ alibi_blocks,
                     const float* __restrict__ alibi_slopes,
                     const int* __restrict__ block_list,
                     const int* __restrict__ block_groups,
                     const int* __restrict__ block_usage,
                     float* __restrict__ out,
                     int U) {
  __shared__ __align__(16) float Kbuf[4][2][32 * DH];  // 128 KiB, per-wave dbuf
  __shared__ __align__(16) float q_lds[QPK * DH];      // scaled query
  __shared__ __align__(16) float p_lds[4][32 * QPK];   // per-wave softmax wts
  __shared__ float combO[4][QPK][DH];
  __shared__ float combM[4][QPK];
  __shared__ float combS[4][QPK];
  __shared__ int   ulist[MAXU];
  __shared__ int   pblds[MAXU];
  __shared__ int   uslds[MAXU];
  __shared__ int   ucount;

  const int tid  = threadIdx.x;
  const int w    = tid >> 6;
  const int lane = tid & 63;
  const int r    = lane & 31;   // token row within wave slice / V granule
  const int half = lane >> 5;
  const int b    = blockIdx.x >> 3;
  const int g    = blockIdx.x & 7;

  // ---- gather this sequence's block entries (order-preserving) + metadata ----
  if (w == 0) {
    int cnt = 0;
    for (int base = 0; base < U; base += 64) {
      const int u = base + lane;
      const bool match = (u < U) && (block_groups[u] == b);
      const unsigned long long mk = __ballot(match);
      if (match) {
        const int pre = __popcll(mk & ((1ull << lane) - 1ull));
        ulist[cnt + pre] = u;
      }
      cnt += __popcll(mk);
    }
    if (lane == 0) ucount = cnt;
    for (int i = lane; i < cnt; i += 64) {
      const int u = ulist[i];
      pblds[i] = block_list[u];
      uslds[i] = block_usage[u];
    }
  }

  // ---- scaled query -> LDS ----
  {
    const float* qsrc = query + ((size_t)b * NH + g * QPK) * DH;
    for (int e = tid; e < QPK * DH; e += 256) q_lds[e] = qsrc[e] * SCALEF;
  }

  float slope[QPK];
#pragma unroll
  for (int qh = 0; qh < QPK; ++qh) slope[qh] = alibi_slopes[g * QPK + qh];

  __syncthreads();  // ulist/pblds/uslds/q_lds visible; vmcnt drained to 0

  const int nblk = ucount;

  float m[QPK], s[QPK], O[QPK][4];
#pragma unroll
  for (int qh = 0; qh < QPK; ++qh) {
    m[qh] = NEG; s[qh] = 0.f;
#pragma unroll
    for (int k = 0; k < 4; ++k) O[qh][k] = 0.f;
  }

  int cur = 0;
  int u_cur = 0, pb_cur = 0, us_cur = 0;
  if (nblk > 0) {
    u_cur = ulist[0]; pb_cur = pblds[0]; us_cur = uslds[0];
    const float* base = key_cache + ((size_t)pb_cur * BS + w * 32) * (KVH * DH) + (size_t)g * DH;
    float* buf = &Kbuf[w][0][0];
#pragma unroll
    for (int i = 0; i < 16; ++i) {
      const int t  = 2 * i + half;
      const int sg = r ^ t;
      __builtin_amdgcn_global_load_lds((const GAS void*)(base + (size_t)t * (KVH * DH) + sg * 4),
                                       (LAS void*)(buf + i * 256), 16, 0, 0);
    }
  }

  for (int c = 0; c < nblk; ++c) {
    // ---- top wait: K[cur] staged (issued one iteration ago) ----
    __builtin_amdgcn_sched_barrier(0);
    asm volatile("s_waitcnt vmcnt(0)" ::: "memory");
    __builtin_amdgcn_sched_barrier(0);

    // ---- (a) alibi issue (oldest vmem) + next-block metadata from LDS ----
    const float ab = alibi_blocks[(size_t)u_cur * BS + w * 32 + r];
    const bool has_nxt = (c + 1 < nblk);
    int u_nxt = 0, pb_nxt = 0, us_nxt = 0;
    if (has_nxt) { u_nxt = ulist[c + 1]; pb_nxt = pblds[c + 1]; us_nxt = uslds[c + 1]; }

    // ---- (b) V loads for current block into registers (issued before the
    //          K-prefetch so their consume waits never drain it) ----
    const float* vb = value_cache + ((size_t)pb_cur * BS + w * 32 + half) * (KVH * DH)
                    + (size_t)g * DH + r * 4;
    float4 vreg[16];
#pragma unroll
    for (int tp = 0; tp < 16; ++tp)
      vreg[tp] = *(const float4*)&vb[(size_t)tp * 2 * (KVH * DH)];

    // ---- (c) stage next block's K into the other buffer ----
    if (has_nxt) {
      const float* base = key_cache + ((size_t)pb_nxt * BS + w * 32) * (KVH * DH) + (size_t)g * DH;
      float* buf = &Kbuf[w][cur ^ 1][0];
#pragma unroll
      for (int i = 0; i < 16; ++i) {
        const int t  = 2 * i + half;
        const int sg = r ^ t;
        __builtin_amdgcn_global_load_lds((const GAS void*)(base + (size_t)t * (KVH * DH) + sg * 4),
                                         (LAS void*)(buf + i * 256), 16, 0, 0);
      }
    }

    // ---- (d) QK on K[cur]: 2 lanes per token, swizzled conflict-free reads ----
    const float* kb = &Kbuf[w][cur][0];
    float acc[QPK] = {0.f, 0.f, 0.f, 0.f};
#pragma unroll
    for (int i = 0; i < 16; ++i) {
      const int j = half * 16 + i;
      const float4 kv = *(const float4*)&kb[r * DH + ((j ^ r) << 2)];
#pragma unroll
      for (int qh = 0; qh < QPK; ++qh) {
        const float4 qv = *(const float4*)&q_lds[qh * DH + (j << 2)];
        acc[qh] += kv.x * qv.x + kv.y * qv.y + kv.z * qv.z + kv.w * qv.w;
      }
    }

    // ---- (e) online softmax over this wave's 32 tokens ----
    const bool valid = (w * 32 + r) < us_cur;
    float p[QPK];
#pragma unroll
    for (int qh = 0; qh < QPK; ++qh) {
      float sc = acc[qh] + __shfl_xor(acc[qh], 32);
      sc += ab * slope[qh];
      if (!valid) sc = NEG;
      float cm = sc;
#pragma unroll
      for (int off = 1; off < 32; off <<= 1) cm = fmaxf(cm, __shfl_xor(cm, off));
      const float mnew = fmaxf(m[qh], cm);
      const float rs   = __expf(m[qh] - mnew);
      m[qh] = mnew;
      p[qh] = valid ? __expf(sc - mnew) : 0.f;
      s[qh] = s[qh] * rs + (half == 0 ? p[qh] : 0.f);
#pragma unroll
      for (int k = 0; k < 4; ++k) O[qh][k] *= rs;
    }
    if (half == 0)
      *(float4*)&p_lds[w][r * 4] = make_float4(p[0], p[1], p[2], p[3]);

    // ---- (f) AV: consume V registers (compiler waits keep prefetch alive) ----
#pragma unroll
    for (int tp = 0; tp < 16; ++tp) {
      const float4 pv = *(const float4*)&p_lds[w][(2 * tp + half) * 4];
      const float4 vv = vreg[tp];
      O[0][0] += pv.x * vv.x; O[0][1] += pv.x * vv.y; O[0][2] += pv.x * vv.z; O[0][3] += pv.x * vv.w;
      O[1][0] += pv.y * vv.x; O[1][1] += pv.y * vv.y; O[1][2] += pv.y * vv.z; O[1][3] += pv.y * vv.w;
      O[2][0] += pv.z * vv.x; O[2][1] += pv.z * vv.y; O[2][2] += pv.z * vv.z; O[2][3] += pv.z * vv.w;
      O[3][0] += pv.w * vv.x; O[3][1] += pv.w * vv.y; O[3][2] += pv.w * vv.z; O[3][3] += pv.w * vv.w;
    }

    u_cur = u_nxt; pb_cur = pb_nxt; us_cur = us_nxt;
    cur ^= 1;
  }

  // ---- per-wave finalize ----
#pragma unroll
  for (int qh = 0; qh < QPK; ++qh) {
    float sv = s[qh];
#pragma unroll
    for (int off = 1; off < 64; off <<= 1) sv += __shfl_xor(sv, off);
#pragma unroll
    for (int k = 0; k < 4; ++k) O[qh][k] += __shfl_xor(O[qh][k], 32);
    if (half == 0) {
#pragma unroll
      for (int k = 0; k < 4; ++k) combO[w][qh][r * 4 + k] = O[qh][k];
    }
    if (lane == 0) { combM[w][qh] = m[qh]; combS[w][qh] = sv; }
  }
  __syncthreads();

  // ---- cross-wave flash combine + output ----
  for (int e = tid; e < QPK * DH; e += 256) {
    const int qh = e >> 7;
    const int d  = e & 127;
    float M = combM[0][qh];
#pragma unroll
    for (int ww = 1; ww < 4; ++ww) M = fmaxf(M, combM[ww][qh]);
    float S = 0.f, Ov = 0.f;
#pragma unroll
    for (int ww = 0; ww < 4; ++ww) {
      const float f = __expf(combM[ww][qh] - M);
      S  += f * combS[ww][qh];
      Ov += f * combO[ww][qh][d];
    }
    out[((size_t)b * NH + g * QPK + qh) * DH + d] = Ov / S;
  }
}

extern "C" void kernel_launch(void* const* d_in, const int* in_sizes, int n_in,
                              void* d_out, int out_size, void* d_ws, size_t ws_size,
                              hipStream_t stream) {
  (void)n_in; (void)out_size; (void)d_ws; (void)ws_size;
  const float* query        = (const float*)d_in[0];
  const float* key_cache    = (const float*)d_in[1];
  const float* value_cache  = (const float*)d_in[2];
  const float* alibi_blocks = (const float*)d_in[3];
  const float* alibi_slopes = (const float*)d_in[4];
  const int*   block_list   = (const int*)d_in[5];
  const int*   block_groups = (const int*)d_in[6];
  const int*   block_usage  = (const int*)d_in[7];
  float*       out          = (float*)d_out;
  const int U = in_sizes[5];

  pa_alibi_decode<<<dim3(BATCH * KVH), dim3(256), 0, stream>>>(
      query, key_cache, value_cache, alibi_blocks, alibi_slopes,
      block_list, block_groups, block_usage, out, U);
}